// Round 3
// baseline (77561.188 us; speedup 1.0000x reference)
//
#include <hip/hip_runtime.h>
#include <hip/hip_bf16.h>
#include <hip/hip_cooperative_groups.h>
#include <math.h>

namespace cg = cooperative_groups;

typedef __attribute__((ext_vector_type(8))) short bf16x8;
typedef __attribute__((ext_vector_type(4))) float f32x4;

// ---- workspace byte offsets ----
#define B_X2    0u            // 512*32*256 bf16 = 8388608
#define B_PM    8388608u      // 32*256*128 f32  = 4194304
#define B_WSA   12582912u     // 4096*1792 bf16  = 14680064
#define B_WSD   27262976u     // 4096*2560 bf16  = 20971520
#define B_WQS   48234496u     // 128*1024 bf16   = 262144
#define B_WPS   48496640u     // 96*1536 bf16    = 294912
#define B_AHB0  48791552u     // 32*1024 bf16
#define B_AHB1  48857088u
#define B_DHB0  48922624u
#define B_DHB1  48988160u
#define B_CTXB  49053696u     // 32*512 bf16
#define B_AC    49086464u     // 32*1024 f32
#define B_DC    49217536u
#define B_AWC   49348608u     // 32*256 f32
#define B_WGT   49381376u     // 32*256 f32
#define B_ZERO_START 48791552u
#define B_ZERO_BYTES 622592u
#define B_PQ    49414144u     // 32*128 f32
#define B_EG    49430528u     // 32*256 f32

// ---- output offsets (floats) ----
#define OUT_GATE  1310720u
#define OUT_ALIGN 1327104u

__device__ __forceinline__ float sigf(float x) { return 1.f / (1.f + expf(-x)); }
__device__ __forceinline__ float ftanh(float x) {
    float t = exp2f(x * 2.885390081777927f);
    return 1.f - 2.f * __builtin_amdgcn_rcpf(t + 1.f);
}

// ============================================================
// Prenet for all timesteps -> bf16 x2[t][b][256]
// ============================================================
__global__ __launch_bounds__(256) void prenet_kernel(
    const float* __restrict__ dec_in,   // (B, 80, 512)
    const float* __restrict__ w1,       // (256, 80)
    const float* __restrict__ w2,       // (256, 256)
    __hip_bfloat16* __restrict__ x2)    // (512, 32, 256) bf16
{
    int b  = blockIdx.x & 31;
    int t0 = (blockIdx.x >> 5) * 16;
    __shared__ float xin[16][80];
    __shared__ float h1[16][257];

    for (int i = threadIdx.x; i < 16 * 80; i += 256) {
        int tt = i / 80, m = i - tt * 80;
        int t = t0 + tt;
        xin[tt][m] = (t == 0) ? 0.f
                   : dec_in[(size_t)b * 80 * 512 + (size_t)m * 512 + (t - 1)];
    }
    __syncthreads();
    for (int i = threadIdx.x; i < 16 * 256; i += 256) {
        int tt = i >> 8, p = i & 255;
        const float* wr = w1 + p * 80;
        float s = 0.f;
        for (int m = 0; m < 80; ++m) s += xin[tt][m] * wr[m];
        h1[tt][p] = fmaxf(s, 0.f);
    }
    __syncthreads();
    for (int i = threadIdx.x; i < 16 * 256; i += 256) {
        int tt = i >> 8, q = i & 255;
        const float* wr = w2 + q * 256;
        float s = 0.f;
        for (int p = 0; p < 256; ++p) s += h1[tt][p] * wr[p];
        int t = t0 + tt;
        x2[(size_t)t * (32 * 256) + b * 256 + q] = __float2bfloat16(fmaxf(s, 0.f));
    }
}

// ============================================================
// processed_memory (f32)
// ============================================================
__global__ __launch_bounds__(128) void pm_kernel(
    const float* __restrict__ memory,   // (32, 256, 512)
    const float* __restrict__ wm,       // (128, 512)
    float* __restrict__ pm)             // (32, 256, 128)
{
    int b = blockIdx.y, tt0 = blockIdx.x * 16;
    __shared__ float ms[16][513];
    for (int i = threadIdx.x; i < 16 * 512; i += 128) {
        int tt = i >> 9, e = i & 511;
        ms[tt][e] = memory[(size_t)b * 131072 + (size_t)(tt0 + tt) * 512 + e];
    }
    __syncthreads();
    int d = threadIdx.x;
    float acc[16];
#pragma unroll
    for (int i = 0; i < 16; ++i) acc[i] = 0.f;
    const float* wr = wm + d * 512;
    for (int e = 0; e < 512; ++e) {
        float w = wr[e];
#pragma unroll
        for (int ttl = 0; ttl < 16; ++ttl) acc[ttl] += w * ms[ttl][e];
    }
    for (int ttl = 0; ttl < 16; ++ttl)
        pm[(size_t)b * 32768 + (size_t)(tt0 + ttl) * 128 + d] = acc[ttl];
}

// ============================================================
// LSTM weight swizzle (gate-interleaved B-frag layout)
// ============================================================
__global__ __launch_bounds__(256) void swizzle_kernel(
    const float* __restrict__ wih, int Kih,
    const float* __restrict__ whh, int Khh,
    __hip_bfloat16* __restrict__ out, int K)
{
    int idx = blockIdx.x * 256 + threadIdx.x;
    int lane = idx & 63;
    int tk = idx >> 6;
    int KB = K >> 5;
    int nt = tk / KB, kb = tk - nt * KB;
    int c = lane & 15;
    int n = (c >> 2) * 1024 + nt * 4 + (c & 3);
    int k = kb * 32 + ((lane >> 4) << 3);
    const float* src; int kk;
    if (k < Kih) { src = wih + (size_t)n * Kih; kk = k; }
    else         { src = whh + (size_t)n * Khh; kk = k - Kih; }
    __hip_bfloat16* op = out + (size_t)idx * 8;
#pragma unroll
    for (int j = 0; j < 8; ++j) op[j] = __float2bfloat16(src[kk + j]);
}

// ============================================================
// wq swizzle (plain B-frag, N=128, K=1024)
// ============================================================
__global__ __launch_bounds__(256) void swizzle_wq(
    const float* __restrict__ wq, __hip_bfloat16* __restrict__ out)
{
    int idx = blockIdx.x * 256 + threadIdx.x;   // 16384
    int lane = idx & 63, tk = idx >> 6;
    int nt2 = tk >> 5, kb = tk & 31;
    int n = nt2 * 16 + (lane & 15);
    int k = kb * 32 + ((lane >> 4) << 3);
    const float* src = wq + (size_t)n * 1024 + k;
    __hip_bfloat16* op = out + (size_t)idx * 8;
#pragma unroll
    for (int j = 0; j < 8; ++j) op[j] = __float2bfloat16(src[j]);
}

// ============================================================
// proj+gate swizzle (N=96: rows 0..79 proj, 80 gate, 81..95 zero; K=1536)
// ============================================================
__global__ __launch_bounds__(256) void swizzle_proj(
    const float* __restrict__ pw, const float* __restrict__ gw,
    __hip_bfloat16* __restrict__ out)
{
    int idx = blockIdx.x * 256 + threadIdx.x;   // 18432
    int lane = idx & 63, tk = idx >> 6;
    int np = tk / 48, kb = tk - np * 48;
    int n = np * 16 + (lane & 15);
    int k = kb * 32 + ((lane >> 4) << 3);
    __hip_bfloat16* op = out + (size_t)idx * 8;
    if (n < 80) {
        const float* src = pw + (size_t)n * 1536 + k;
#pragma unroll
        for (int j = 0; j < 8; ++j) op[j] = __float2bfloat16(src[j]);
    } else if (n == 80) {
        const float* src = gw + k;
#pragma unroll
        for (int j = 0; j < 8; ++j) op[j] = __float2bfloat16(src[j]);
    } else {
#pragma unroll
        for (int j = 0; j < 8; ++j) op[j] = __float2bfloat16(0.f);
    }
}

// ============================================================
// Persistent decoder: 256 blocks x 512 threads, cooperative
// ============================================================
__global__ __launch_bounds__(512, 2) void decoder_persistent(
    const float* __restrict__ memory,
    const int* __restrict__ mlen,
    const float* __restrict__ a_bias,
    const float* __restrict__ d_bias,
    const float* __restrict__ proj_b,
    const float* __restrict__ gate_b,
    const float* __restrict__ loc_conv,
    const float* __restrict__ loc_dense,
    const float* __restrict__ vvec,
    char* __restrict__ ws,
    float* __restrict__ out)
{
    cg::grid_group grid = cg::this_grid();

    const __hip_bfloat16* x2b = (const __hip_bfloat16*)(ws + B_X2);
    const float* pm   = (const float*)(ws + B_PM);
    const bf16x8* wsA = (const bf16x8*)(ws + B_WSA);
    const bf16x8* wsD = (const bf16x8*)(ws + B_WSD);
    const bf16x8* wqs = (const bf16x8*)(ws + B_WQS);
    const bf16x8* wps = (const bf16x8*)(ws + B_WPS);
    __hip_bfloat16* ahbuf[2] = { (__hip_bfloat16*)(ws + B_AHB0), (__hip_bfloat16*)(ws + B_AHB1) };
    __hip_bfloat16* dhbuf[2] = { (__hip_bfloat16*)(ws + B_DHB0), (__hip_bfloat16*)(ws + B_DHB1) };
    __hip_bfloat16* ctxb = (__hip_bfloat16*)(ws + B_CTXB);
    float* ac    = (float*)(ws + B_AC);
    float* dc    = (float*)(ws + B_DC);
    float* awc_g = (float*)(ws + B_AWC);
    float* wgt_g = (float*)(ws + B_WGT);
    float* pq_g  = (float*)(ws + B_PQ);
    float* e_g   = (float*)(ws + B_EG);
    float* out_mel   = out;
    float* out_gate  = out + OUT_GATE;
    float* out_align = out + OUT_ALIGN;

    int tid = threadIdx.x, lane = tid & 63, w = tid >> 6;
    int nt = blockIdx.x, b8 = nt >> 3, s8 = nt & 7;
    int r0 = lane & 15, kq = (lane >> 4) << 3;

    __shared__ float ck_a[32][34];
    __shared__ float ck_b[32][34];
    __shared__ __hip_bfloat16 ldense_b[4096];
    __shared__ float aw_s[68];
    __shared__ float awc_s[68];
    __shared__ __hip_bfloat16 loc_b[32][40];
    __shared__ float locp[32][132];
    __shared__ float red[8][2][4][64];
    __shared__ float gsum[32][17];
    __shared__ float wgt_sh[256];
    __shared__ float sm_r[16];

    // ---- LDS constants (once) ----
    for (int i = tid; i < 1024; i += 512) {
        int f = i >> 5, k = i & 31;
        ck_a[f][k] = (k < 31) ? loc_conv[f * 62 + k] : 0.f;
        ck_b[f][k] = (k < 31) ? loc_conv[f * 62 + 31 + k] : 0.f;
    }
    for (int i = tid; i < 4096; i += 512) {
        int l2 = i >> 3, j = i & 7;
        int la = l2 & 63, tc = l2 >> 6;
        int d = tc * 16 + (la & 15);
        int k = ((la >> 4) << 3) + j;
        ldense_b[i] = __float2bfloat16(loc_dense[d * 32 + k]);
    }

    // ---- pin LSTM weights in registers ----
    bf16x8 wA[7], wD[10];
    {
        const bf16x8* p = wsA + ((size_t)nt * 56 + (size_t)w * 7) * 64 + lane;
#pragma unroll
        for (int i = 0; i < 7; ++i) wA[i] = p[i * 64];
        const bf16x8* pd = wsD + ((size_t)nt * 80 + (size_t)w * 10) * 64 + lane;
#pragma unroll
        for (int i = 0; i < 10; ++i) wD[i] = pd[i * 64];
    }
    int len = mlen[b8];
    float* redf = &red[0][0][0][0];
    __syncthreads();

#pragma unroll 1
    for (int t = 0; t <= 512; ++t) {
        // ================= PHASE 1: A(t) || D(t-1) + conv(t) =================
        f32x4 accA0 = {0,0,0,0}, accA1 = {0,0,0,0};
        f32x4 accD0 = {0,0,0,0}, accD1 = {0,0,0,0};
        if (t < 512) {
            const __hip_bfloat16* ahp = ahbuf[t & 1];
            const __hip_bfloat16* x2p = x2b + (size_t)t * 8192;
            int k0 = w * 224;
#pragma unroll
            for (int i = 0; i < 7; ++i) {
                int kc = k0 + i * 32;
                const __hip_bfloat16* sp; int sstr, off;
                if (kc < 256)      { sp = x2p;  sstr = 256;  off = kc; }
                else if (kc < 768) { sp = ctxb; sstr = 512;  off = kc - 256; }
                else               { sp = ahp;  sstr = 1024; off = kc - 768; }
                bf16x8 a0 = *(const bf16x8*)(sp + (size_t)r0 * sstr + off + kq);
                bf16x8 a1 = *(const bf16x8*)(sp + (size_t)(r0 + 16) * sstr + off + kq);
                accA0 = __builtin_amdgcn_mfma_f32_16x16x32_bf16(a0, wA[i], accA0, 0, 0, 0);
                accA1 = __builtin_amdgcn_mfma_f32_16x16x32_bf16(a1, wA[i], accA1, 0, 0, 0);
            }
        }
        if (t > 0) {
            const __hip_bfloat16* ahp = ahbuf[t & 1];          // ah(t-1)
            const __hip_bfloat16* dhp = dhbuf[(t - 1) & 1];    // dh(t-2)
            int k0 = w * 320;
#pragma unroll
            for (int i = 0; i < 10; ++i) {
                int kc = k0 + i * 32;
                const __hip_bfloat16* sp; int sstr, off;
                if (kc < 1024)      { sp = ahp;  sstr = 1024; off = kc; }
                else if (kc < 1536) { sp = ctxb; sstr = 512;  off = kc - 1024; }
                else                { sp = dhp;  sstr = 1024; off = kc - 1536; }
                bf16x8 a0 = *(const bf16x8*)(sp + (size_t)r0 * sstr + off + kq);
                bf16x8 a1 = *(const bf16x8*)(sp + (size_t)(r0 + 16) * sstr + off + kq);
                accD0 = __builtin_amdgcn_mfma_f32_16x16x32_bf16(a0, wD[i], accD0, 0, 0, 0);
                accD1 = __builtin_amdgcn_mfma_f32_16x16x32_bf16(a1, wD[i], accD1, 0, 0, 0);
            }
        }
        if (t < 512) {
            // conv staging + compute
            if (tid < 64) {
                int g = s8 * 32 - 15 + tid;
                bool ok = (g >= 0) && (g < 256);
                aw_s[tid]  = ok ? wgt_g[b8 * 256 + g] : 0.f;
                awc_s[tid] = ok ? awc_g[b8 * 256 + g] : 0.f;
            }
            __syncthreads();
            {
                int f = tid & 31, ttg = tid >> 5;
                int o = ttg * 2;
                float2 awin[17], cwin[17];
#pragma unroll
                for (int i = 0; i < 17; ++i) {
                    awin[i] = *(const float2*)&aw_s[o + 2 * i];
                    cwin[i] = *(const float2*)&awc_s[o + 2 * i];
                }
                float o0 = 0.f, o1 = 0.f;
#pragma unroll
                for (int kp = 0; kp < 16; ++kp) {
                    float2 ka  = *(const float2*)&ck_a[f][2 * kp];
                    float2 kb2 = *(const float2*)&ck_b[f][2 * kp];
                    o0 += ka.x * awin[kp].x + ka.y * awin[kp].y
                        + kb2.x * cwin[kp].x + kb2.y * cwin[kp].y;
                    o1 += ka.x * awin[kp].y + kb2.x * cwin[kp].y
                        + ka.y * awin[kp + 1].x + kb2.y * cwin[kp + 1].x;
                }
                loc_b[o][f]     = __float2bfloat16(o0);
                loc_b[o + 1][f] = __float2bfloat16(o1);
            }
            // reduce + epilogue A
#pragma unroll
            for (int r = 0; r < 4; ++r) {
                red[w][0][r][lane] = accA0[r];
                red[w][1][r][lane] = accA1[r];
            }
            __syncthreads();
            {
                int bb = tid >> 4, c = tid & 15;
                int mt = bb >> 4, bm = bb & 15;
                int lidx = ((bm >> 2) << 4) + c, rg = bm & 3;
                float s = 0.f;
#pragma unroll
                for (int k = 0; k < 8; ++k) s += red[k][mt][rg][lidx];
                gsum[bb][c] = s;
            }
            __syncthreads();
            if (tid < 128) {
                int bb = tid & 31, jl = tid >> 5;
                int j = nt * 4 + jl;
                float gi = gsum[bb][jl]      + a_bias[j];
                float gf = gsum[bb][4 + jl]  + a_bias[1024 + j];
                float gg = gsum[bb][8 + jl]  + a_bias[2048 + j];
                float go = gsum[bb][12 + jl] + a_bias[3072 + j];
                float cv = ac[bb * 1024 + j];
                float c2 = sigf(gf) * cv + sigf(gi) * tanhf(gg);
                float h2 = sigf(go) * tanhf(c2);
                ac[bb * 1024 + j] = c2;
                ahbuf[(t + 1) & 1][bb * 1024 + j] = __float2bfloat16(h2);
            }
        }
        if (t > 0) {
            __syncthreads();
#pragma unroll
            for (int r = 0; r < 4; ++r) {
                red[w][0][r][lane] = accD0[r];
                red[w][1][r][lane] = accD1[r];
            }
            __syncthreads();
            {
                int bb = tid >> 4, c = tid & 15;
                int mt = bb >> 4, bm = bb & 15;
                int lidx = ((bm >> 2) << 4) + c, rg = bm & 3;
                float s = 0.f;
#pragma unroll
                for (int k = 0; k < 8; ++k) s += red[k][mt][rg][lidx];
                gsum[bb][c] = s;
            }
            __syncthreads();
            if (tid < 128) {
                int bb = tid & 31, jl = tid >> 5;
                int j = nt * 4 + jl;
                float gi = gsum[bb][jl]      + d_bias[j];
                float gf = gsum[bb][4 + jl]  + d_bias[1024 + j];
                float gg = gsum[bb][8 + jl]  + d_bias[2048 + j];
                float go = gsum[bb][12 + jl] + d_bias[3072 + j];
                float cv = dc[bb * 1024 + j];
                float c2 = sigf(gf) * cv + sigf(gi) * tanhf(gg);
                float h2 = sigf(go) * tanhf(c2);
                dc[bb * 1024 + j] = c2;
                dhbuf[t & 1][bb * 1024 + j] = __float2bfloat16(h2);
            }
        }
        grid.sync();

        // ================= PHASE 2: locproj || pq(t) || proj(t-1) ============
        if (t < 512) {
            int mt = w & 1;
            bf16x8 Af = *(const bf16x8*)&loc_b[mt * 16 + r0][kq];
#pragma unroll
            for (int u = 0; u < 2; ++u) {
                int tc = (w >> 1) * 2 + u;
                bf16x8 Bf = *(const bf16x8*)&ldense_b[(tc * 64 + lane) * 8];
                f32x4 z = {0,0,0,0};
                f32x4 P = __builtin_amdgcn_mfma_f32_16x16x32_bf16(Af, Bf, z, 0, 0, 0);
#pragma unroll
                for (int r = 0; r < 4; ++r)
                    locp[mt * 16 + (lane >> 4) * 4 + r][tc * 16 + r0] = P[r];
            }
        }
        if (nt < 16 && t < 512) {
            int mt = nt & 1, nt2 = nt >> 1;
            const __hip_bfloat16* ahc = ahbuf[(t + 1) & 1];
            f32x4 acc = {0,0,0,0};
#pragma unroll
            for (int i = 0; i < 4; ++i) {
                int kc = w * 4 + i;
                bf16x8 a = *(const bf16x8*)(ahc + (size_t)(mt * 16 + r0) * 1024 + kc * 32 + kq);
                bf16x8 bb = wqs[((size_t)nt2 * 32 + kc) * 64 + lane];
                acc = __builtin_amdgcn_mfma_f32_16x16x32_bf16(a, bb, acc, 0, 0, 0);
            }
#pragma unroll
            for (int r = 0; r < 4; ++r) red[w][0][r][lane] = acc[r];
            __syncthreads();
            if (tid < 64) {
#pragma unroll
                for (int r = 0; r < 4; ++r) {
                    float s = 0.f;
#pragma unroll
                    for (int k = 0; k < 8; ++k) s += red[k][0][r][tid];
                    pq_g[(mt * 16 + (tid >> 4) * 4 + r) * 128 + nt2 * 16 + (tid & 15)] = s;
                }
            }
        } else if (nt >= 16 && nt < 28 && t > 0) {
            int p2 = nt - 16, mt = p2 & 1, np = p2 >> 1;
            const __hip_bfloat16* dhp = dhbuf[t & 1];   // dh(t-1)
            f32x4 acc = {0,0,0,0};
#pragma unroll
            for (int i = 0; i < 6; ++i) {
                int kc = w * 6 + i;
                int kbase = kc * 32;
                const __hip_bfloat16* sp; int sstr, off;
                if (kbase < 1024) { sp = dhp;  sstr = 1024; off = kbase; }
                else              { sp = ctxb; sstr = 512;  off = kbase - 1024; }
                bf16x8 a = *(const bf16x8*)(sp + (size_t)(mt * 16 + r0) * sstr + off + kq);
                bf16x8 bb = wps[((size_t)np * 48 + kc) * 64 + lane];
                acc = __builtin_amdgcn_mfma_f32_16x16x32_bf16(a, bb, acc, 0, 0, 0);
            }
#pragma unroll
            for (int r = 0; r < 4; ++r) red[w][0][r][lane] = acc[r];
            __syncthreads();
            if (tid < 64) {
#pragma unroll
                for (int r = 0; r < 4; ++r) {
                    float s = 0.f;
#pragma unroll
                    for (int k = 0; k < 8; ++k) s += red[k][0][r][tid];
                    int n = np * 16 + (tid & 15);
                    int bb2 = mt * 16 + (tid >> 4) * 4 + r;
                    if (n < 80)
                        out_mel[(size_t)bb2 * 40960 + (size_t)n * 512 + (t - 1)] = s + proj_b[n];
                    else if (n == 80)
                        out_gate[bb2 * 512 + (t - 1)] = s + gate_b[0];
                }
            }
        }
        if (t == 512) break;
        grid.sync();

        // ================= PHASE 3: energies =================
        {
            int tt_l = tid >> 4, dg = tid & 15;
            int tt = s8 * 32 + tt_l;
            const float* pqr = pq_g + b8 * 128 + dg * 8;
            const float* pmr = pm + ((size_t)b8 << 15) + (size_t)tt * 128 + dg * 8;
            const float* vr  = vvec + dg * 8;
            float s = 0.f;
#pragma unroll
            for (int h = 0; h < 2; ++h) {
                float4 lp  = *(const float4*)&locp[tt_l][dg * 8 + h * 4];
                float4 pq4 = *(const float4*)(pqr + h * 4);
                float4 pm4 = *(const float4*)(pmr + h * 4);
                float4 v4  = *(const float4*)(vr + h * 4);
                s += ftanh(lp.x + pq4.x + pm4.x) * v4.x;
                s += ftanh(lp.y + pq4.y + pm4.y) * v4.y;
                s += ftanh(lp.z + pq4.z + pm4.z) * v4.z;
                s += ftanh(lp.w + pq4.w + pm4.w) * v4.w;
            }
#pragma unroll
            for (int m = 1; m < 16; m <<= 1) s += __shfl_xor(s, m);
            if (dg == 0) e_g[b8 * 256 + tt] = s;
        }
        grid.sync();

        // ================= PHASE 4: softmax + ctx + state =================
        {
            float e = -3.0e38f, exv = 0.f;
            if (tid < 256) e = (tid < len) ? e_g[b8 * 256 + tid] : -1e9f;
            float m1 = e;
#pragma unroll
            for (int m = 1; m < 64; m <<= 1) m1 = fmaxf(m1, __shfl_xor(m1, m));
            if (tid < 256 && lane == 0) sm_r[w] = m1;
            __syncthreads();
            float mx = fmaxf(fmaxf(sm_r[0], sm_r[1]), fmaxf(sm_r[2], sm_r[3]));
            if (tid < 256) {
                exv = exp2f((e - mx) * 1.4426950408889634f);
                wgt_sh[tid] = exv;
            }
            float s1 = exv;
#pragma unroll
            for (int m = 1; m < 64; m <<= 1) s1 += __shfl_xor(s1, m);
            if (lane == 0) sm_r[8 + w] = s1;
            __syncthreads();
            float tot = sm_r[8] + sm_r[9] + sm_r[10] + sm_r[11];
            float winv = 1.f / tot;
            if (s8 == 0 && tid < 256) {
                float wg = wgt_sh[tid] * winv;
                out_align[(size_t)b8 * 131072 + (size_t)t * 256 + tid] = wg;
                wgt_g[b8 * 256 + tid] = wg;
                awc_g[b8 * 256 + tid] += wg;
            }
            int eo = tid & 63, p = tid >> 6;
            const float* mr = memory + (size_t)b8 * 131072 + s8 * 64 + eo;
            float cs = 0.f;
#pragma unroll 4
            for (int i = 0; i < 32; ++i) {
                int tt = p * 32 + i;
                cs = fmaf(wgt_sh[tt], mr[(size_t)tt * 512], cs);
            }
            redf[p * 64 + eo] = cs;
            __syncthreads();
            if (tid < 64) {
                float s = 0.f;
#pragma unroll
                for (int pp = 0; pp < 8; ++pp) s += redf[pp * 64 + tid];
                ctxb[b8 * 512 + s8 * 64 + tid] = __float2bfloat16(s * winv);
            }
        }
        grid.sync();
    }
}

// ============================================================
extern "C" void kernel_launch(void* const* d_in, const int* in_sizes, int n_in,
                              void* d_out, int out_size, void* d_ws, size_t ws_size,
                              hipStream_t stream)
{
    const float* memory   = (const float*)d_in[0];
    const float* dec_in   = (const float*)d_in[1];
    const int*   mlen     = (const int*)  d_in[2];
    const float* pw1      = (const float*)d_in[3];
    const float* pw2      = (const float*)d_in[4];
    const float* a_wih    = (const float*)d_in[5];
    const float* a_whh    = (const float*)d_in[6];
    const float* a_b      = (const float*)d_in[7];
    const float* wq       = (const float*)d_in[8];
    const float* wm       = (const float*)d_in[9];
    const float* v        = (const float*)d_in[10];
    const float* lconv    = (const float*)d_in[11];
    const float* ldense   = (const float*)d_in[12];
    const float* d_wih    = (const float*)d_in[13];
    const float* d_whh    = (const float*)d_in[14];
    const float* d_b      = (const float*)d_in[15];
    const float* proj_w   = (const float*)d_in[16];
    const float* proj_b   = (const float*)d_in[17];
    const float* gate_w   = (const float*)d_in[18];
    const float* gate_b   = (const float*)d_in[19];

    char* ws = (char*)d_ws;
    __hip_bfloat16* x2b  = (__hip_bfloat16*)(ws + B_X2);
    float*          pm   = (float*)(ws + B_PM);
    __hip_bfloat16* wswA = (__hip_bfloat16*)(ws + B_WSA);
    __hip_bfloat16* wswD = (__hip_bfloat16*)(ws + B_WSD);
    __hip_bfloat16* wqs  = (__hip_bfloat16*)(ws + B_WQS);
    __hip_bfloat16* wps  = (__hip_bfloat16*)(ws + B_WPS);
    float* outbase = (float*)d_out;

    hipMemsetAsync(ws + B_ZERO_START, 0, B_ZERO_BYTES, stream);

    prenet_kernel<<<1024, 256, 0, stream>>>(dec_in, pw1, pw2, x2b);
    pm_kernel<<<dim3(16, 32), 128, 0, stream>>>(memory, wm, pm);
    swizzle_kernel<<<3584, 256, 0, stream>>>(a_wih, 768,  a_whh, 1024, wswA, 1792);
    swizzle_kernel<<<5120, 256, 0, stream>>>(d_wih, 1536, d_whh, 1024, wswD, 2560);
    swizzle_wq<<<64, 256, 0, stream>>>(wq, wqs);
    swizzle_proj<<<72, 256, 0, stream>>>(proj_w, gate_w, wps);

    void* kargs[] = {
        (void*)&memory, (void*)&mlen, (void*)&a_b, (void*)&d_b,
        (void*)&proj_b, (void*)&gate_b, (void*)&lconv, (void*)&ldense,
        (void*)&v, (void*)&ws, (void*)&outbase
    };
    hipLaunchCooperativeKernel((void*)decoder_persistent, dim3(256), dim3(512),
                               kargs, 0, stream);
}

// Round 4
// 70461.902 us; speedup vs baseline: 1.1008x; 1.1008x over previous
//
#include <hip/hip_runtime.h>
#include <hip/hip_bf16.h>
#include <math.h>

typedef __attribute__((ext_vector_type(8))) short bf16x8;
typedef __attribute__((ext_vector_type(4))) float f32x4;

// ---- workspace byte offsets ----
#define B_X2    0u            // 512*32*256 bf16 = 8388608
#define B_PM    8388608u      // 32*256*128 f32  = 4194304
#define B_WSA   12582912u     // 4096*1792 bf16  = 14680064
#define B_WSD   27262976u     // 4096*2560 bf16  = 20971520
#define B_WQS   48234496u     // 128*1024 bf16   = 262144
#define B_WPS   48496640u     // 96*1536 bf16    = 294912
#define B_AHB0  48791552u     // 32*1024 bf16
#define B_AHB1  48857088u
#define B_DHB0  48922624u
#define B_DHB1  48988160u
#define B_CTXB  49053696u     // 32*512 bf16
#define B_AC    49086464u     // 32*1024 f32
#define B_DC    49217536u
#define B_AWC   49348608u     // 32*256 f32
#define B_WGT   49381376u     // 32*256 f32
#define B_ZERO_START 48791552u
#define B_ZERO_BYTES 622592u
#define B_PQ    49414144u     // 32*128 f32
#define B_EG    49430528u     // 32*256 f32
#define B_BAR   49463296u     // barrier counter (zeroed separately)

// ---- output offsets (floats) ----
#define OUT_GATE  1310720u
#define OUT_ALIGN 1327104u

__device__ __forceinline__ float sigf(float x) { return 1.f / (1.f + expf(-x)); }
__device__ __forceinline__ float ftanh(float x) {
    float t = exp2f(x * 2.885390081777927f);
    return 1.f - 2.f * __builtin_amdgcn_rcpf(t + 1.f);
}

// Lightweight grid barrier: leader arrives (agent-scope acq_rel add), spins on
// monotone target. Acquire load invalidates L1 for the whole CU (1 block/CU).
__device__ __forceinline__ void grid_barrier(int* cnt, int target) {
    __syncthreads();
    if (threadIdx.x == 0) {
        __hip_atomic_fetch_add(cnt, 1, __ATOMIC_ACQ_REL, __HIP_MEMORY_SCOPE_AGENT);
        while (__hip_atomic_load(cnt, __ATOMIC_ACQUIRE, __HIP_MEMORY_SCOPE_AGENT) < target) {
            __builtin_amdgcn_s_sleep(2);
        }
    }
    __syncthreads();
}

// ============================================================
// Prenet for all timesteps -> bf16 x2[t][b][256]
// ============================================================
__global__ __launch_bounds__(256) void prenet_kernel(
    const float* __restrict__ dec_in,   // (B, 80, 512)
    const float* __restrict__ w1,       // (256, 80)
    const float* __restrict__ w2,       // (256, 256)
    __hip_bfloat16* __restrict__ x2)    // (512, 32, 256) bf16
{
    int b  = blockIdx.x & 31;
    int t0 = (blockIdx.x >> 5) * 16;
    __shared__ float xin[16][80];
    __shared__ float h1[16][257];

    for (int i = threadIdx.x; i < 16 * 80; i += 256) {
        int tt = i / 80, m = i - tt * 80;
        int t = t0 + tt;
        xin[tt][m] = (t == 0) ? 0.f
                   : dec_in[(size_t)b * 80 * 512 + (size_t)m * 512 + (t - 1)];
    }
    __syncthreads();
    for (int i = threadIdx.x; i < 16 * 256; i += 256) {
        int tt = i >> 8, p = i & 255;
        const float* wr = w1 + p * 80;
        float s = 0.f;
        for (int m = 0; m < 80; ++m) s += xin[tt][m] * wr[m];
        h1[tt][p] = fmaxf(s, 0.f);
    }
    __syncthreads();
    for (int i = threadIdx.x; i < 16 * 256; i += 256) {
        int tt = i >> 8, q = i & 255;
        const float* wr = w2 + q * 256;
        float s = 0.f;
        for (int p = 0; p < 256; ++p) s += h1[tt][p] * wr[p];
        int t = t0 + tt;
        x2[(size_t)t * (32 * 256) + b * 256 + q] = __float2bfloat16(fmaxf(s, 0.f));
    }
}

// ============================================================
// processed_memory (f32)
// ============================================================
__global__ __launch_bounds__(128) void pm_kernel(
    const float* __restrict__ memory,   // (32, 256, 512)
    const float* __restrict__ wm,       // (128, 512)
    float* __restrict__ pm)             // (32, 256, 128)
{
    int b = blockIdx.y, tt0 = blockIdx.x * 16;
    __shared__ float ms[16][513];
    for (int i = threadIdx.x; i < 16 * 512; i += 128) {
        int tt = i >> 9, e = i & 511;
        ms[tt][e] = memory[(size_t)b * 131072 + (size_t)(tt0 + tt) * 512 + e];
    }
    __syncthreads();
    int d = threadIdx.x;
    float acc[16];
#pragma unroll
    for (int i = 0; i < 16; ++i) acc[i] = 0.f;
    const float* wr = wm + d * 512;
    for (int e = 0; e < 512; ++e) {
        float w = wr[e];
#pragma unroll
        for (int ttl = 0; ttl < 16; ++ttl) acc[ttl] += w * ms[ttl][e];
    }
    for (int ttl = 0; ttl < 16; ++ttl)
        pm[(size_t)b * 32768 + (size_t)(tt0 + ttl) * 128 + d] = acc[ttl];
}

// ============================================================
// LSTM weight swizzle (gate-interleaved B-frag layout)
// ============================================================
__global__ __launch_bounds__(256) void swizzle_kernel(
    const float* __restrict__ wih, int Kih,
    const float* __restrict__ whh, int Khh,
    __hip_bfloat16* __restrict__ out, int K)
{
    int idx = blockIdx.x * 256 + threadIdx.x;
    int lane = idx & 63;
    int tk = idx >> 6;
    int KB = K >> 5;
    int nt = tk / KB, kb = tk - nt * KB;
    int c = lane & 15;
    int n = (c >> 2) * 1024 + nt * 4 + (c & 3);
    int k = kb * 32 + ((lane >> 4) << 3);
    const float* src; int kk;
    if (k < Kih) { src = wih + (size_t)n * Kih; kk = k; }
    else         { src = whh + (size_t)n * Khh; kk = k - Kih; }
    __hip_bfloat16* op = out + (size_t)idx * 8;
#pragma unroll
    for (int j = 0; j < 8; ++j) op[j] = __float2bfloat16(src[kk + j]);
}

// ============================================================
// wq swizzle (plain B-frag, N=128, K=1024)
// ============================================================
__global__ __launch_bounds__(256) void swizzle_wq(
    const float* __restrict__ wq, __hip_bfloat16* __restrict__ out)
{
    int idx = blockIdx.x * 256 + threadIdx.x;   // 16384
    int lane = idx & 63, tk = idx >> 6;
    int nt2 = tk >> 5, kb = tk & 31;
    int n = nt2 * 16 + (lane & 15);
    int k = kb * 32 + ((lane >> 4) << 3);
    const float* src = wq + (size_t)n * 1024 + k;
    __hip_bfloat16* op = out + (size_t)idx * 8;
#pragma unroll
    for (int j = 0; j < 8; ++j) op[j] = __float2bfloat16(src[j]);
}

// ============================================================
// proj+gate swizzle (N=96: rows 0..79 proj, 80 gate, 81..95 zero; K=1536)
// ============================================================
__global__ __launch_bounds__(256) void swizzle_proj(
    const float* __restrict__ pw, const float* __restrict__ gw,
    __hip_bfloat16* __restrict__ out)
{
    int idx = blockIdx.x * 256 + threadIdx.x;   // 18432
    int lane = idx & 63, tk = idx >> 6;
    int np = tk / 48, kb = tk - np * 48;
    int n = np * 16 + (lane & 15);
    int k = kb * 32 + ((lane >> 4) << 3);
    __hip_bfloat16* op = out + (size_t)idx * 8;
    if (n < 80) {
        const float* src = pw + (size_t)n * 1536 + k;
#pragma unroll
        for (int j = 0; j < 8; ++j) op[j] = __float2bfloat16(src[j]);
    } else if (n == 80) {
        const float* src = gw + k;
#pragma unroll
        for (int j = 0; j < 8; ++j) op[j] = __float2bfloat16(src[j]);
    } else {
#pragma unroll
        for (int j = 0; j < 8; ++j) op[j] = __float2bfloat16(0.f);
    }
}

// ============================================================
// Persistent decoder: 256 blocks x 512 threads, cooperative
// wA in regs (28 VGPRs), wD in LDS (80 KB) -- no spills.
// ============================================================
__global__ __launch_bounds__(512, 2) void decoder_persistent(
    const float* __restrict__ memory,
    const int* __restrict__ mlen,
    const float* __restrict__ a_bias,
    const float* __restrict__ d_bias,
    const float* __restrict__ proj_b,
    const float* __restrict__ gate_b,
    const float* __restrict__ loc_conv,
    const float* __restrict__ loc_dense,
    const float* __restrict__ vvec,
    char* __restrict__ ws,
    float* __restrict__ out)
{
    const __hip_bfloat16* x2b = (const __hip_bfloat16*)(ws + B_X2);
    const float* pm   = (const float*)(ws + B_PM);
    const bf16x8* wsA = (const bf16x8*)(ws + B_WSA);
    const bf16x8* wsD = (const bf16x8*)(ws + B_WSD);
    const bf16x8* wqs = (const bf16x8*)(ws + B_WQS);
    const bf16x8* wps = (const bf16x8*)(ws + B_WPS);
    __hip_bfloat16* ahbuf[2] = { (__hip_bfloat16*)(ws + B_AHB0), (__hip_bfloat16*)(ws + B_AHB1) };
    __hip_bfloat16* dhbuf[2] = { (__hip_bfloat16*)(ws + B_DHB0), (__hip_bfloat16*)(ws + B_DHB1) };
    __hip_bfloat16* ctxb = (__hip_bfloat16*)(ws + B_CTXB);
    float* ac    = (float*)(ws + B_AC);
    float* dc    = (float*)(ws + B_DC);
    float* awc_g = (float*)(ws + B_AWC);
    float* wgt_g = (float*)(ws + B_WGT);
    float* pq_g  = (float*)(ws + B_PQ);
    float* e_g   = (float*)(ws + B_EG);
    int*   bar   = (int*)(ws + B_BAR);
    float* out_mel   = out;
    float* out_gate  = out + OUT_GATE;
    float* out_align = out + OUT_ALIGN;

    int tid = threadIdx.x, lane = tid & 63, w = tid >> 6;
    int nt = blockIdx.x, b8 = nt >> 3, s8 = nt & 7;
    int r0 = lane & 15, kq = (lane >> 4) << 3;

    __shared__ bf16x8 wD_lds[5120];          // 80 KB: D-LSTM B-fragments
    __shared__ float ck_a[32][34];
    __shared__ float ck_b[32][34];
    __shared__ __hip_bfloat16 ldense_b[4096];
    __shared__ float aw_s[68];
    __shared__ float awc_s[68];
    __shared__ __hip_bfloat16 loc_b[32][40];
    __shared__ float locp[32][132];
    __shared__ float red[8][2][4][64];
    __shared__ float gsum[32][17];
    __shared__ float wgt_sh[256];
    __shared__ float sm_r[16];

    // ---- LDS constants + D weights (once) ----
    for (int i = tid; i < 1024; i += 512) {
        int f = i >> 5, k = i & 31;
        ck_a[f][k] = (k < 31) ? loc_conv[f * 62 + k] : 0.f;
        ck_b[f][k] = (k < 31) ? loc_conv[f * 62 + 31 + k] : 0.f;
    }
    for (int i = tid; i < 4096; i += 512) {
        int l2 = i >> 3, j = i & 7;
        int la = l2 & 63, tc = l2 >> 6;
        int d = tc * 16 + (la & 15);
        int k = ((la >> 4) << 3) + j;
        ldense_b[i] = __float2bfloat16(loc_dense[d * 32 + k]);
    }
    for (int i = tid; i < 5120; i += 512)
        wD_lds[i] = wsD[(size_t)nt * 5120 + i];

    // ---- pin A-LSTM weights in registers (28 VGPRs) ----
    bf16x8 wA[7];
    {
        const bf16x8* p = wsA + ((size_t)nt * 56 + (size_t)w * 7) * 64 + lane;
#pragma unroll
        for (int i = 0; i < 7; ++i) wA[i] = p[i * 64];
    }
    int len = mlen[b8];
    float* redf = &red[0][0][0][0];
    int gen = 0;
    __syncthreads();

#pragma unroll 1
    for (int t = 0; t <= 512; ++t) {
        // ================= PHASE 1: A(t) || D(t-1) + conv(t) =================
        f32x4 accA0 = {0,0,0,0}, accA1 = {0,0,0,0};
        f32x4 accD0 = {0,0,0,0}, accD1 = {0,0,0,0};
        if (t < 512) {
            const __hip_bfloat16* ahp = ahbuf[t & 1];
            const __hip_bfloat16* x2p = x2b + (size_t)t * 8192;
            int k0 = w * 224;
#pragma unroll
            for (int i = 0; i < 7; ++i) {
                int kc = k0 + i * 32;
                const __hip_bfloat16* sp; int sstr, off;
                if (kc < 256)      { sp = x2p;  sstr = 256;  off = kc; }
                else if (kc < 768) { sp = ctxb; sstr = 512;  off = kc - 256; }
                else               { sp = ahp;  sstr = 1024; off = kc - 768; }
                bf16x8 a0 = *(const bf16x8*)(sp + (size_t)r0 * sstr + off + kq);
                bf16x8 a1 = *(const bf16x8*)(sp + (size_t)(r0 + 16) * sstr + off + kq);
                accA0 = __builtin_amdgcn_mfma_f32_16x16x32_bf16(a0, wA[i], accA0, 0, 0, 0);
                accA1 = __builtin_amdgcn_mfma_f32_16x16x32_bf16(a1, wA[i], accA1, 0, 0, 0);
            }
        }
        if (t > 0) {
            const __hip_bfloat16* ahp = ahbuf[t & 1];          // ah(t-1)
            const __hip_bfloat16* dhp = dhbuf[(t - 1) & 1];    // dh(t-2)
            int k0 = w * 320;
#pragma unroll
            for (int i = 0; i < 10; ++i) {
                int kc = k0 + i * 32;
                const __hip_bfloat16* sp; int sstr, off;
                if (kc < 1024)      { sp = ahp;  sstr = 1024; off = kc; }
                else if (kc < 1536) { sp = ctxb; sstr = 512;  off = kc - 1024; }
                else                { sp = dhp;  sstr = 1024; off = kc - 1536; }
                bf16x8 a0 = *(const bf16x8*)(sp + (size_t)r0 * sstr + off + kq);
                bf16x8 a1 = *(const bf16x8*)(sp + (size_t)(r0 + 16) * sstr + off + kq);
                bf16x8 bb = wD_lds[(w * 10 + i) * 64 + lane];
                accD0 = __builtin_amdgcn_mfma_f32_16x16x32_bf16(a0, bb, accD0, 0, 0, 0);
                accD1 = __builtin_amdgcn_mfma_f32_16x16x32_bf16(a1, bb, accD1, 0, 0, 0);
            }
        }
        if (t < 512) {
            // conv staging + compute
            if (tid < 64) {
                int g = s8 * 32 - 15 + tid;
                bool ok = (g >= 0) && (g < 256);
                aw_s[tid]  = ok ? wgt_g[b8 * 256 + g] : 0.f;
                awc_s[tid] = ok ? awc_g[b8 * 256 + g] : 0.f;
            }
            __syncthreads();
            {
                int f = tid & 31, ttg = tid >> 5;
                int o = ttg * 2;
                float2 awin[17], cwin[17];
#pragma unroll
                for (int i = 0; i < 17; ++i) {
                    awin[i] = *(const float2*)&aw_s[o + 2 * i];
                    cwin[i] = *(const float2*)&awc_s[o + 2 * i];
                }
                float o0 = 0.f, o1 = 0.f;
#pragma unroll
                for (int kp = 0; kp < 16; ++kp) {
                    float2 ka  = *(const float2*)&ck_a[f][2 * kp];
                    float2 kb2 = *(const float2*)&ck_b[f][2 * kp];
                    o0 += ka.x * awin[kp].x + ka.y * awin[kp].y
                        + kb2.x * cwin[kp].x + kb2.y * cwin[kp].y;
                    o1 += ka.x * awin[kp].y + kb2.x * cwin[kp].y
                        + ka.y * awin[kp + 1].x + kb2.y * cwin[kp + 1].x;
                }
                loc_b[o][f]     = __float2bfloat16(o0);
                loc_b[o + 1][f] = __float2bfloat16(o1);
            }
            // reduce + epilogue A
#pragma unroll
            for (int r = 0; r < 4; ++r) {
                red[w][0][r][lane] = accA0[r];
                red[w][1][r][lane] = accA1[r];
            }
            __syncthreads();
            {
                int bb = tid >> 4, c = tid & 15;
                int mt = bb >> 4, bm = bb & 15;
                int lidx = ((bm >> 2) << 4) + c, rg = bm & 3;
                float s = 0.f;
#pragma unroll
                for (int k = 0; k < 8; ++k) s += red[k][mt][rg][lidx];
                gsum[bb][c] = s;
            }
            __syncthreads();
            if (tid < 128) {
                int bb = tid & 31, jl = tid >> 5;
                int j = nt * 4 + jl;
                float gi = gsum[bb][jl]      + a_bias[j];
                float gf = gsum[bb][4 + jl]  + a_bias[1024 + j];
                float gg = gsum[bb][8 + jl]  + a_bias[2048 + j];
                float go = gsum[bb][12 + jl] + a_bias[3072 + j];
                float cv = ac[bb * 1024 + j];
                float c2 = sigf(gf) * cv + sigf(gi) * tanhf(gg);
                float h2 = sigf(go) * tanhf(c2);
                ac[bb * 1024 + j] = c2;
                ahbuf[(t + 1) & 1][bb * 1024 + j] = __float2bfloat16(h2);
            }
        }
        if (t > 0) {
            __syncthreads();
#pragma unroll
            for (int r = 0; r < 4; ++r) {
                red[w][0][r][lane] = accD0[r];
                red[w][1][r][lane] = accD1[r];
            }
            __syncthreads();
            {
                int bb = tid >> 4, c = tid & 15;
                int mt = bb >> 4, bm = bb & 15;
                int lidx = ((bm >> 2) << 4) + c, rg = bm & 3;
                float s = 0.f;
#pragma unroll
                for (int k = 0; k < 8; ++k) s += red[k][mt][rg][lidx];
                gsum[bb][c] = s;
            }
            __syncthreads();
            if (tid < 128) {
                int bb = tid & 31, jl = tid >> 5;
                int j = nt * 4 + jl;
                float gi = gsum[bb][jl]      + d_bias[j];
                float gf = gsum[bb][4 + jl]  + d_bias[1024 + j];
                float gg = gsum[bb][8 + jl]  + d_bias[2048 + j];
                float go = gsum[bb][12 + jl] + d_bias[3072 + j];
                float cv = dc[bb * 1024 + j];
                float c2 = sigf(gf) * cv + sigf(gi) * tanhf(gg);
                float h2 = sigf(go) * tanhf(c2);
                dc[bb * 1024 + j] = c2;
                dhbuf[t & 1][bb * 1024 + j] = __float2bfloat16(h2);
            }
        }
        grid_barrier(bar, ++gen * 256);

        // ================= PHASE 2: locproj || pq(t) || proj(t-1) ============
        if (t < 512) {
            int mt = w & 1;
            bf16x8 Af = *(const bf16x8*)&loc_b[mt * 16 + r0][kq];
#pragma unroll
            for (int u = 0; u < 2; ++u) {
                int tc = (w >> 1) * 2 + u;
                bf16x8 Bf = *(const bf16x8*)&ldense_b[(tc * 64 + lane) * 8];
                f32x4 z = {0,0,0,0};
                f32x4 P = __builtin_amdgcn_mfma_f32_16x16x32_bf16(Af, Bf, z, 0, 0, 0);
#pragma unroll
                for (int r = 0; r < 4; ++r)
                    locp[mt * 16 + (lane >> 4) * 4 + r][tc * 16 + r0] = P[r];
            }
        }
        if (nt < 16 && t < 512) {
            int mt = nt & 1, nt2 = nt >> 1;
            const __hip_bfloat16* ahc = ahbuf[(t + 1) & 1];
            f32x4 acc = {0,0,0,0};
#pragma unroll
            for (int i = 0; i < 4; ++i) {
                int kc = w * 4 + i;
                bf16x8 a = *(const bf16x8*)(ahc + (size_t)(mt * 16 + r0) * 1024 + kc * 32 + kq);
                bf16x8 bb = wqs[((size_t)nt2 * 32 + kc) * 64 + lane];
                acc = __builtin_amdgcn_mfma_f32_16x16x32_bf16(a, bb, acc, 0, 0, 0);
            }
#pragma unroll
            for (int r = 0; r < 4; ++r) red[w][0][r][lane] = acc[r];
            __syncthreads();
            if (tid < 64) {
#pragma unroll
                for (int r = 0; r < 4; ++r) {
                    float s = 0.f;
#pragma unroll
                    for (int k = 0; k < 8; ++k) s += red[k][0][r][tid];
                    pq_g[(mt * 16 + (tid >> 4) * 4 + r) * 128 + nt2 * 16 + (tid & 15)] = s;
                }
            }
        } else if (nt >= 16 && nt < 28 && t > 0) {
            int p2 = nt - 16, mt = p2 & 1, np = p2 >> 1;
            const __hip_bfloat16* dhp = dhbuf[t & 1];   // dh(t-1)
            f32x4 acc = {0,0,0,0};
#pragma unroll
            for (int i = 0; i < 6; ++i) {
                int kc = w * 6 + i;
                int kbase = kc * 32;
                const __hip_bfloat16* sp; int sstr, off;
                if (kbase < 1024) { sp = dhp;  sstr = 1024; off = kbase; }
                else              { sp = ctxb; sstr = 512;  off = kbase - 1024; }
                bf16x8 a = *(const bf16x8*)(sp + (size_t)(mt * 16 + r0) * sstr + off + kq);
                bf16x8 bb = wps[((size_t)np * 48 + kc) * 64 + lane];
                acc = __builtin_amdgcn_mfma_f32_16x16x32_bf16(a, bb, acc, 0, 0, 0);
            }
#pragma unroll
            for (int r = 0; r < 4; ++r) red[w][0][r][lane] = acc[r];
            __syncthreads();
            if (tid < 64) {
#pragma unroll
                for (int r = 0; r < 4; ++r) {
                    float s = 0.f;
#pragma unroll
                    for (int k = 0; k < 8; ++k) s += red[k][0][r][tid];
                    int n = np * 16 + (tid & 15);
                    int bb2 = mt * 16 + (tid >> 4) * 4 + r;
                    if (n < 80)
                        out_mel[(size_t)bb2 * 40960 + (size_t)n * 512 + (t - 1)] = s + proj_b[n];
                    else if (n == 80)
                        out_gate[bb2 * 512 + (t - 1)] = s + gate_b[0];
                }
            }
        }
        if (t == 512) break;
        grid_barrier(bar, ++gen * 256);

        // ================= PHASE 3: energies =================
        {
            int tt_l = tid >> 4, dg = tid & 15;
            int tt = s8 * 32 + tt_l;
            const float* pqr = pq_g + b8 * 128 + dg * 8;
            const float* pmr = pm + ((size_t)b8 << 15) + (size_t)tt * 128 + dg * 8;
            const float* vr  = vvec + dg * 8;
            float s = 0.f;
#pragma unroll
            for (int h = 0; h < 2; ++h) {
                float4 lp  = *(const float4*)&locp[tt_l][dg * 8 + h * 4];
                float4 pq4 = *(const float4*)(pqr + h * 4);
                float4 pm4 = *(const float4*)(pmr + h * 4);
                float4 v4  = *(const float4*)(vr + h * 4);
                s += ftanh(lp.x + pq4.x + pm4.x) * v4.x;
                s += ftanh(lp.y + pq4.y + pm4.y) * v4.y;
                s += ftanh(lp.z + pq4.z + pm4.z) * v4.z;
                s += ftanh(lp.w + pq4.w + pm4.w) * v4.w;
            }
#pragma unroll
            for (int m = 1; m < 16; m <<= 1) s += __shfl_xor(s, m);
            if (dg == 0) e_g[b8 * 256 + tt] = s;
        }
        grid_barrier(bar, ++gen * 256);

        // ================= PHASE 4: softmax + ctx + state =================
        {
            float e = -3.0e38f, exv = 0.f;
            if (tid < 256) e = (tid < len) ? e_g[b8 * 256 + tid] : -1e9f;
            float m1 = e;
#pragma unroll
            for (int m = 1; m < 64; m <<= 1) m1 = fmaxf(m1, __shfl_xor(m1, m));
            if (tid < 256 && lane == 0) sm_r[w] = m1;
            __syncthreads();
            float mx = fmaxf(fmaxf(sm_r[0], sm_r[1]), fmaxf(sm_r[2], sm_r[3]));
            if (tid < 256) {
                exv = exp2f((e - mx) * 1.4426950408889634f);
                wgt_sh[tid] = exv;
            }
            float s1 = exv;
#pragma unroll
            for (int m = 1; m < 64; m <<= 1) s1 += __shfl_xor(s1, m);
            if (lane == 0) sm_r[8 + w] = s1;
            __syncthreads();
            float tot = sm_r[8] + sm_r[9] + sm_r[10] + sm_r[11];
            float winv = 1.f / tot;
            if (s8 == 0 && tid < 256) {
                float wg = wgt_sh[tid] * winv;
                out_align[(size_t)b8 * 131072 + (size_t)t * 256 + tid] = wg;
                wgt_g[b8 * 256 + tid] = wg;
                awc_g[b8 * 256 + tid] += wg;
            }
            int eo = tid & 63, p = tid >> 6;
            const float* mr = memory + (size_t)b8 * 131072 + s8 * 64 + eo;
            float cs = 0.f;
#pragma unroll 4
            for (int i = 0; i < 32; ++i) {
                int tt = p * 32 + i;
                cs = fmaf(wgt_sh[tt], mr[(size_t)tt * 512], cs);
            }
            redf[p * 64 + eo] = cs;
            __syncthreads();
            if (tid < 64) {
                float s = 0.f;
#pragma unroll
                for (int pp = 0; pp < 8; ++pp) s += redf[pp * 64 + tid];
                ctxb[b8 * 512 + s8 * 64 + tid] = __float2bfloat16(s * winv);
            }
        }
        grid_barrier(bar, ++gen * 256);
    }
}

// ============================================================
extern "C" void kernel_launch(void* const* d_in, const int* in_sizes, int n_in,
                              void* d_out, int out_size, void* d_ws, size_t ws_size,
                              hipStream_t stream)
{
    const float* memory   = (const float*)d_in[0];
    const float* dec_in   = (const float*)d_in[1];
    const int*   mlen     = (const int*)  d_in[2];
    const float* pw1      = (const float*)d_in[3];
    const float* pw2      = (const float*)d_in[4];
    const float* a_wih    = (const float*)d_in[5];
    const float* a_whh    = (const float*)d_in[6];
    const float* a_b      = (const float*)d_in[7];
    const float* wq       = (const float*)d_in[8];
    const float* wm       = (const float*)d_in[9];
    const float* v        = (const float*)d_in[10];
    const float* lconv    = (const float*)d_in[11];
    const float* ldense   = (const float*)d_in[12];
    const float* d_wih    = (const float*)d_in[13];
    const float* d_whh    = (const float*)d_in[14];
    const float* d_b      = (const float*)d_in[15];
    const float* proj_w   = (const float*)d_in[16];
    const float* proj_b   = (const float*)d_in[17];
    const float* gate_w   = (const float*)d_in[18];
    const float* gate_b   = (const float*)d_in[19];

    char* ws = (char*)d_ws;
    __hip_bfloat16* x2b  = (__hip_bfloat16*)(ws + B_X2);
    float*          pm   = (float*)(ws + B_PM);
    __hip_bfloat16* wswA = (__hip_bfloat16*)(ws + B_WSA);
    __hip_bfloat16* wswD = (__hip_bfloat16*)(ws + B_WSD);
    __hip_bfloat16* wqs  = (__hip_bfloat16*)(ws + B_WQS);
    __hip_bfloat16* wps  = (__hip_bfloat16*)(ws + B_WPS);
    float* outbase = (float*)d_out;

    hipMemsetAsync(ws + B_ZERO_START, 0, B_ZERO_BYTES, stream);
    hipMemsetAsync(ws + B_BAR, 0, 64, stream);

    prenet_kernel<<<1024, 256, 0, stream>>>(dec_in, pw1, pw2, x2b);
    pm_kernel<<<dim3(16, 32), 128, 0, stream>>>(memory, wm, pm);
    swizzle_kernel<<<3584, 256, 0, stream>>>(a_wih, 768,  a_whh, 1024, wswA, 1792);
    swizzle_kernel<<<5120, 256, 0, stream>>>(d_wih, 1536, d_whh, 1024, wswD, 2560);
    swizzle_wq<<<64, 256, 0, stream>>>(wq, wqs);
    swizzle_proj<<<72, 256, 0, stream>>>(proj_w, gate_w, wps);

    void* kargs[] = {
        (void*)&memory, (void*)&mlen, (void*)&a_b, (void*)&d_b,
        (void*)&proj_b, (void*)&gate_b, (void*)&lconv, (void*)&ldense,
        (void*)&v, (void*)&ws, (void*)&outbase
    };
    hipLaunchCooperativeKernel((void*)decoder_persistent, dim3(256), dim3(512),
                               kargs, 0, stream);
}

// Round 5
// 49561.240 us; speedup vs baseline: 1.5650x; 1.4217x over previous
//
#include <hip/hip_runtime.h>
#include <hip/hip_bf16.h>
#include <math.h>

typedef __attribute__((ext_vector_type(8))) short bf16x8;
typedef __attribute__((ext_vector_type(4))) float f32x4;

// ---- workspace byte offsets ----
#define B_X2    0u            // 512*32*256 bf16 = 8388608
#define B_PM    8388608u      // 32*256*128 f32  = 4194304
#define B_WSA   12582912u     // 4096*1792 bf16  = 14680064
#define B_WSD   27262976u     // 4096*2560 bf16  = 20971520
#define B_WQS   48234496u     // 128*1024 bf16   = 262144
#define B_WPS   48496640u     // 96*1536 bf16    = 294912
#define B_AHB0  48791552u     // 32*1024 bf16
#define B_AHB1  48857088u
#define B_DHB0  48922624u
#define B_DHB1  48988160u
#define B_CTX0  49053696u     // 32*512 bf16
#define B_CTX1  49086464u
#define B_AC    49119232u     // 32*1024 f32
#define B_DC    49250304u
#define B_AWC   49381376u     // 32*256 f32
#define B_WGT   49414144u     // 32*256 f32
#define B_ZERO_START 48791552u
#define B_ZERO_BYTES 655360u
#define B_PQ    49446912u     // 32*128 f32
#define B_EG    49463296u     // 32*256 f32
#define B_GBAR  49496064u     // 256 slots x 64B grid barrier
#define B_PQF   49512448u     // 16 slots x 64B pq flags
#define B_EFL   49513472u     // 256 slots x 64B e flags
#define B_BAR_ZERO_BYTES 33792u

// ---- output offsets (floats) ----
#define OUT_GATE  1310720u
#define OUT_ALIGN 1327104u

__device__ __forceinline__ float sigf(float x) { return 1.f / (1.f + expf(-x)); }
__device__ __forceinline__ float ftanh(float x) {
    float t = exp2f(x * 2.885390081777927f);
    return 1.f - 2.f * __builtin_amdgcn_rcpf(t + 1.f);
}

// Parallel-arrival grid barrier: block i release-stores gen to its own padded
// slot; 256 spinner threads each acquire-poll one slot. No RMW serialization.
__device__ __forceinline__ void grid_barrier(int* slots, int gen) {
    __syncthreads();
    if (threadIdx.x == 0)
        __hip_atomic_store(slots + blockIdx.x * 16, gen, __ATOMIC_RELEASE,
                           __HIP_MEMORY_SCOPE_AGENT);
    if (threadIdx.x < 256) {
        int* p = slots + threadIdx.x * 16;
        while (__hip_atomic_load(p, __ATOMIC_ACQUIRE, __HIP_MEMORY_SCOPE_AGENT) < gen) {}
    }
    __syncthreads();
}

// ============================================================
// Prenet for all timesteps -> bf16 x2[t][b][256]
// ============================================================
__global__ __launch_bounds__(256) void prenet_kernel(
    const float* __restrict__ dec_in,
    const float* __restrict__ w1,
    const float* __restrict__ w2,
    __hip_bfloat16* __restrict__ x2)
{
    int b  = blockIdx.x & 31;
    int t0 = (blockIdx.x >> 5) * 16;
    __shared__ float xin[16][80];
    __shared__ float h1[16][257];

    for (int i = threadIdx.x; i < 16 * 80; i += 256) {
        int tt = i / 80, m = i - tt * 80;
        int t = t0 + tt;
        xin[tt][m] = (t == 0) ? 0.f
                   : dec_in[(size_t)b * 80 * 512 + (size_t)m * 512 + (t - 1)];
    }
    __syncthreads();
    for (int i = threadIdx.x; i < 16 * 256; i += 256) {
        int tt = i >> 8, p = i & 255;
        const float* wr = w1 + p * 80;
        float s = 0.f;
        for (int m = 0; m < 80; ++m) s += xin[tt][m] * wr[m];
        h1[tt][p] = fmaxf(s, 0.f);
    }
    __syncthreads();
    for (int i = threadIdx.x; i < 16 * 256; i += 256) {
        int tt = i >> 8, q = i & 255;
        const float* wr = w2 + q * 256;
        float s = 0.f;
        for (int p = 0; p < 256; ++p) s += h1[tt][p] * wr[p];
        int t = t0 + tt;
        x2[(size_t)t * (32 * 256) + b * 256 + q] = __float2bfloat16(fmaxf(s, 0.f));
    }
}

// ============================================================
// processed_memory (f32)
// ============================================================
__global__ __launch_bounds__(128) void pm_kernel(
    const float* __restrict__ memory,
    const float* __restrict__ wm,
    float* __restrict__ pm)
{
    int b = blockIdx.y, tt0 = blockIdx.x * 16;
    __shared__ float ms[16][513];
    for (int i = threadIdx.x; i < 16 * 512; i += 128) {
        int tt = i >> 9, e = i & 511;
        ms[tt][e] = memory[(size_t)b * 131072 + (size_t)(tt0 + tt) * 512 + e];
    }
    __syncthreads();
    int d = threadIdx.x;
    float acc[16];
#pragma unroll
    for (int i = 0; i < 16; ++i) acc[i] = 0.f;
    const float* wr = wm + d * 512;
    for (int e = 0; e < 512; ++e) {
        float w = wr[e];
#pragma unroll
        for (int ttl = 0; ttl < 16; ++ttl) acc[ttl] += w * ms[ttl][e];
    }
    for (int ttl = 0; ttl < 16; ++ttl)
        pm[(size_t)b * 32768 + (size_t)(tt0 + ttl) * 128 + d] = acc[ttl];
}

// ============================================================
// LSTM weight swizzle (gate-interleaved B-frag layout)
// ============================================================
__global__ __launch_bounds__(256) void swizzle_kernel(
    const float* __restrict__ wih, int Kih,
    const float* __restrict__ whh, int Khh,
    __hip_bfloat16* __restrict__ out, int K)
{
    int idx = blockIdx.x * 256 + threadIdx.x;
    int lane = idx & 63;
    int tk = idx >> 6;
    int KB = K >> 5;
    int nt = tk / KB, kb = tk - nt * KB;
    int c = lane & 15;
    int n = (c >> 2) * 1024 + nt * 4 + (c & 3);
    int k = kb * 32 + ((lane >> 4) << 3);
    const float* src; int kk;
    if (k < Kih) { src = wih + (size_t)n * Kih; kk = k; }
    else         { src = whh + (size_t)n * Khh; kk = k - Kih; }
    __hip_bfloat16* op = out + (size_t)idx * 8;
#pragma unroll
    for (int j = 0; j < 8; ++j) op[j] = __float2bfloat16(src[kk + j]);
}

// ============================================================
// wq swizzle (plain B-frag, N=128, K=1024)
// ============================================================
__global__ __launch_bounds__(256) void swizzle_wq(
    const float* __restrict__ wq, __hip_bfloat16* __restrict__ out)
{
    int idx = blockIdx.x * 256 + threadIdx.x;
    int lane = idx & 63, tk = idx >> 6;
    int nt2 = tk >> 5, kb = tk & 31;
    int n = nt2 * 16 + (lane & 15);
    int k = kb * 32 + ((lane >> 4) << 3);
    const float* src = wq + (size_t)n * 1024 + k;
    __hip_bfloat16* op = out + (size_t)idx * 8;
#pragma unroll
    for (int j = 0; j < 8; ++j) op[j] = __float2bfloat16(src[j]);
}

// ============================================================
// proj+gate swizzle
// ============================================================
__global__ __launch_bounds__(256) void swizzle_proj(
    const float* __restrict__ pw, const float* __restrict__ gw,
    __hip_bfloat16* __restrict__ out)
{
    int idx = blockIdx.x * 256 + threadIdx.x;
    int lane = idx & 63, tk = idx >> 6;
    int np = tk / 48, kb = tk - np * 48;
    int n = np * 16 + (lane & 15);
    int k = kb * 32 + ((lane >> 4) << 3);
    __hip_bfloat16* op = out + (size_t)idx * 8;
    if (n < 80) {
        const float* src = pw + (size_t)n * 1536 + k;
#pragma unroll
        for (int j = 0; j < 8; ++j) op[j] = __float2bfloat16(src[j]);
    } else if (n == 80) {
        const float* src = gw + k;
#pragma unroll
        for (int j = 0; j < 8; ++j) op[j] = __float2bfloat16(src[j]);
    } else {
#pragma unroll
        for (int j = 0; j < 8; ++j) op[j] = __float2bfloat16(0.f);
    }
}

// ============================================================
// Persistent decoder: 256 blocks x 512 threads, cooperative
// 2 grid syncs + 2 padded-flag waits per step.
// ============================================================
__global__ __launch_bounds__(512, 2) void decoder_persistent(
    const float* __restrict__ memory,
    const int* __restrict__ mlen,
    const float* __restrict__ a_bias,
    const float* __restrict__ d_bias,
    const float* __restrict__ proj_b,
    const float* __restrict__ gate_b,
    const float* __restrict__ loc_conv,
    const float* __restrict__ loc_dense,
    const float* __restrict__ vvec,
    char* __restrict__ ws,
    float* __restrict__ out)
{
    const __hip_bfloat16* x2b = (const __hip_bfloat16*)(ws + B_X2);
    const float* pm   = (const float*)(ws + B_PM);
    const bf16x8* wsA = (const bf16x8*)(ws + B_WSA);
    const bf16x8* wsD = (const bf16x8*)(ws + B_WSD);
    const bf16x8* wqs = (const bf16x8*)(ws + B_WQS);
    const bf16x8* wps = (const bf16x8*)(ws + B_WPS);
    __hip_bfloat16* ahbuf[2] = { (__hip_bfloat16*)(ws + B_AHB0), (__hip_bfloat16*)(ws + B_AHB1) };
    __hip_bfloat16* dhbuf[2] = { (__hip_bfloat16*)(ws + B_DHB0), (__hip_bfloat16*)(ws + B_DHB1) };
    __hip_bfloat16* ctxbuf[2] = { (__hip_bfloat16*)(ws + B_CTX0), (__hip_bfloat16*)(ws + B_CTX1) };
    float* ac    = (float*)(ws + B_AC);
    float* dc    = (float*)(ws + B_DC);
    float* awc_g = (float*)(ws + B_AWC);
    float* wgt_g = (float*)(ws + B_WGT);
    float* pq_g  = (float*)(ws + B_PQ);
    float* e_g   = (float*)(ws + B_EG);
    int* gslots  = (int*)(ws + B_GBAR);
    int* pq_flag = (int*)(ws + B_PQF);
    int* e_flag  = (int*)(ws + B_EFL);
    float* out_mel   = out;
    float* out_gate  = out + OUT_GATE;
    float* out_align = out + OUT_ALIGN;

    int tid = threadIdx.x, lane = tid & 63, w = tid >> 6;
    int nt = blockIdx.x, b8 = nt >> 3, s8 = nt & 7;
    int r0 = lane & 15, kq = (lane >> 4) << 3;

    __shared__ bf16x8 wD_lds[5120];          // 80 KB
    __shared__ float ck_a[32][34];
    __shared__ float ck_b[32][34];
    __shared__ __hip_bfloat16 ldense_b[4096];
    __shared__ float aw_s[68];
    __shared__ float awc_s[68];
    __shared__ __hip_bfloat16 loc_b[32][40];
    __shared__ float locp[32][132];
    __shared__ float red[8][2][4][64];
    __shared__ float gsum[32][17];
    __shared__ float wgt_sh[256];
    __shared__ float sm_r[16];

    for (int i = tid; i < 1024; i += 512) {
        int f = i >> 5, k = i & 31;
        ck_a[f][k] = (k < 31) ? loc_conv[f * 62 + k] : 0.f;
        ck_b[f][k] = (k < 31) ? loc_conv[f * 62 + 31 + k] : 0.f;
    }
    for (int i = tid; i < 4096; i += 512) {
        int l2 = i >> 3, j = i & 7;
        int la = l2 & 63, tc = l2 >> 6;
        int d = tc * 16 + (la & 15);
        int k = ((la >> 4) << 3) + j;
        ldense_b[i] = __float2bfloat16(loc_dense[d * 32 + k]);
    }
    for (int i = tid; i < 5120; i += 512)
        wD_lds[i] = wsD[(size_t)nt * 5120 + i];

    bf16x8 wA[7];
    {
        const bf16x8* p = wsA + ((size_t)nt * 56 + (size_t)w * 7) * 64 + lane;
#pragma unroll
        for (int i = 0; i < 7; ++i) wA[i] = p[i * 64];
    }
    int len = mlen[b8];
    float* redf = &red[0][0][0][0];
    __syncthreads();

#pragma unroll 1
    for (int t = 0; t <= 512; ++t) {
        __hip_bfloat16* ctx_prev = ctxbuf[(t + 1) & 1];
        __hip_bfloat16* ctx_cur  = ctxbuf[t & 1];

        // ================= W1: A(t) || D(t-1) + conv(t) =================
        f32x4 accA0 = {0,0,0,0}, accA1 = {0,0,0,0};
        f32x4 accD0 = {0,0,0,0}, accD1 = {0,0,0,0};
        if (t < 512) {
            const __hip_bfloat16* ahp = ahbuf[t & 1];
            const __hip_bfloat16* x2p = x2b + (size_t)t * 8192;
            int k0 = w * 224;
#pragma unroll
            for (int i = 0; i < 7; ++i) {
                int kc = k0 + i * 32;
                const __hip_bfloat16* sp; int sstr, off;
                if (kc < 256)      { sp = x2p;      sstr = 256;  off = kc; }
                else if (kc < 768) { sp = ctx_prev; sstr = 512;  off = kc - 256; }
                else               { sp = ahp;      sstr = 1024; off = kc - 768; }
                bf16x8 a0 = *(const bf16x8*)(sp + (size_t)r0 * sstr + off + kq);
                bf16x8 a1 = *(const bf16x8*)(sp + (size_t)(r0 + 16) * sstr + off + kq);
                accA0 = __builtin_amdgcn_mfma_f32_16x16x32_bf16(a0, wA[i], accA0, 0, 0, 0);
                accA1 = __builtin_amdgcn_mfma_f32_16x16x32_bf16(a1, wA[i], accA1, 0, 0, 0);
            }
        }
        if (t > 0) {
            const __hip_bfloat16* ahp = ahbuf[t & 1];          // ah(t-1)
            const __hip_bfloat16* dhp = dhbuf[(t - 1) & 1];    // dh(t-2)
            int k0 = w * 320;
#pragma unroll
            for (int i = 0; i < 10; ++i) {
                int kc = k0 + i * 32;
                const __hip_bfloat16* sp; int sstr, off;
                if (kc < 1024)      { sp = ahp;      sstr = 1024; off = kc; }
                else if (kc < 1536) { sp = ctx_prev; sstr = 512;  off = kc - 1024; }
                else                { sp = dhp;      sstr = 1024; off = kc - 1536; }
                bf16x8 a0 = *(const bf16x8*)(sp + (size_t)r0 * sstr + off + kq);
                bf16x8 a1 = *(const bf16x8*)(sp + (size_t)(r0 + 16) * sstr + off + kq);
                bf16x8 bb = wD_lds[(w * 10 + i) * 64 + lane];
                accD0 = __builtin_amdgcn_mfma_f32_16x16x32_bf16(a0, bb, accD0, 0, 0, 0);
                accD1 = __builtin_amdgcn_mfma_f32_16x16x32_bf16(a1, bb, accD1, 0, 0, 0);
            }
        }
        if (t < 512) {
            if (tid < 64) {
                int g = s8 * 32 - 15 + tid;
                bool ok = (g >= 0) && (g < 256);
                aw_s[tid]  = ok ? wgt_g[b8 * 256 + g] : 0.f;
                awc_s[tid] = ok ? awc_g[b8 * 256 + g] : 0.f;
            }
            __syncthreads();
            {
                // conv: LDS-direct taps (no register windows -> no spills)
                int f = tid & 31, ttg = tid >> 5;
                int o = ttg * 2;
                float o0 = 0.f, o1 = 0.f;
#pragma unroll
                for (int k = 0; k < 31; ++k) {
                    float ka  = ck_a[f][k], kb2 = ck_b[f][k];
                    float a0 = aw_s[o + k],     c0 = awc_s[o + k];
                    float a1 = aw_s[o + 1 + k], c1 = awc_s[o + 1 + k];
                    o0 = fmaf(ka, a0, fmaf(kb2, c0, o0));
                    o1 = fmaf(ka, a1, fmaf(kb2, c1, o1));
                }
                loc_b[o][f]     = __float2bfloat16(o0);
                loc_b[o + 1][f] = __float2bfloat16(o1);
            }
#pragma unroll
            for (int r = 0; r < 4; ++r) {
                red[w][0][r][lane] = accA0[r];
                red[w][1][r][lane] = accA1[r];
            }
            __syncthreads();
            {
                int bb = tid >> 4, c = tid & 15;
                int mt = bb >> 4, bm = bb & 15;
                int lidx = ((bm >> 2) << 4) + c, rg = bm & 3;
                float s = 0.f;
#pragma unroll
                for (int k = 0; k < 8; ++k) s += red[k][mt][rg][lidx];
                gsum[bb][c] = s;
            }
            __syncthreads();
            if (tid < 128) {
                int bb = tid & 31, jl = tid >> 5;
                int j = nt * 4 + jl;
                float gi = gsum[bb][jl]      + a_bias[j];
                float gf = gsum[bb][4 + jl]  + a_bias[1024 + j];
                float gg = gsum[bb][8 + jl]  + a_bias[2048 + j];
                float go = gsum[bb][12 + jl] + a_bias[3072 + j];
                float cv = ac[bb * 1024 + j];
                float c2 = sigf(gf) * cv + sigf(gi) * tanhf(gg);
                float h2 = sigf(go) * tanhf(c2);
                ac[bb * 1024 + j] = c2;
                ahbuf[(t + 1) & 1][bb * 1024 + j] = __float2bfloat16(h2);
            }
        }
        if (t > 0) {
            __syncthreads();
#pragma unroll
            for (int r = 0; r < 4; ++r) {
                red[w][0][r][lane] = accD0[r];
                red[w][1][r][lane] = accD1[r];
            }
            __syncthreads();
            {
                int bb = tid >> 4, c = tid & 15;
                int mt = bb >> 4, bm = bb & 15;
                int lidx = ((bm >> 2) << 4) + c, rg = bm & 3;
                float s = 0.f;
#pragma unroll
                for (int k = 0; k < 8; ++k) s += red[k][mt][rg][lidx];
                gsum[bb][c] = s;
            }
            __syncthreads();
            if (tid < 128) {
                int bb = tid & 31, jl = tid >> 5;
                int j = nt * 4 + jl;
                float gi = gsum[bb][jl]      + d_bias[j];
                float gf = gsum[bb][4 + jl]  + d_bias[1024 + j];
                float gg = gsum[bb][8 + jl]  + d_bias[2048 + j];
                float go = gsum[bb][12 + jl] + d_bias[3072 + j];
                float cv = dc[bb * 1024 + j];
                float c2 = sigf(gf) * cv + sigf(gi) * tanhf(gg);
                float h2 = sigf(go) * tanhf(c2);
                dc[bb * 1024 + j] = c2;
                dhbuf[t & 1][bb * 1024 + j] = __float2bfloat16(h2);
            }
        }
        grid_barrier(gslots, 2 * t + 1);

        // ================= W2 =================
        // pq producers (blocks 0..15): tile (mt = nt&1, nt2 = nt>>1)
        if (nt < 16 && t < 512) {
            int mt = nt & 1, nt2 = nt >> 1;
            const __hip_bfloat16* ahc = ahbuf[(t + 1) & 1];
            f32x4 acc = {0,0,0,0};
#pragma unroll
            for (int i = 0; i < 4; ++i) {
                int kc = w * 4 + i;
                bf16x8 a = *(const bf16x8*)(ahc + (size_t)(mt * 16 + r0) * 1024 + kc * 32 + kq);
                bf16x8 bb = wqs[((size_t)nt2 * 32 + kc) * 64 + lane];
                acc = __builtin_amdgcn_mfma_f32_16x16x32_bf16(a, bb, acc, 0, 0, 0);
            }
#pragma unroll
            for (int r = 0; r < 4; ++r) red[w][0][r][lane] = acc[r];
            __syncthreads();
            if (tid < 64) {
#pragma unroll
                for (int r = 0; r < 4; ++r) {
                    float s = 0.f;
#pragma unroll
                    for (int k = 0; k < 8; ++k) s += red[k][0][r][tid];
                    pq_g[(mt * 16 + (tid >> 4) * 4 + r) * 128 + nt2 * 16 + (tid & 15)] = s;
                }
            }
            __syncthreads();
            if (tid == 0)
                __hip_atomic_store(pq_flag + (mt * 8 + nt2) * 16, t + 1,
                                   __ATOMIC_RELEASE, __HIP_MEMORY_SCOPE_AGENT);
        }
        // proj blocks (16..27): proj(t-1)
        if (nt >= 16 && nt < 28 && t > 0) {
            int p2 = nt - 16, mt = p2 & 1, np = p2 >> 1;
            const __hip_bfloat16* dhp = dhbuf[t & 1];   // dh(t-1)
            f32x4 acc = {0,0,0,0};
#pragma unroll
            for (int i = 0; i < 6; ++i) {
                int kc = w * 6 + i;
                int kbase = kc * 32;
                const __hip_bfloat16* sp; int sstr, off;
                if (kbase < 1024) { sp = dhp;      sstr = 1024; off = kbase; }
                else              { sp = ctx_prev; sstr = 512;  off = kbase - 1024; }
                bf16x8 a = *(const bf16x8*)(sp + (size_t)(mt * 16 + r0) * sstr + off + kq);
                bf16x8 bb = wps[((size_t)np * 48 + kc) * 64 + lane];
                acc = __builtin_amdgcn_mfma_f32_16x16x32_bf16(a, bb, acc, 0, 0, 0);
            }
#pragma unroll
            for (int r = 0; r < 4; ++r) red[w][0][r][lane] = acc[r];
            __syncthreads();
            if (tid < 64) {
#pragma unroll
                for (int r = 0; r < 4; ++r) {
                    float s = 0.f;
#pragma unroll
                    for (int k = 0; k < 8; ++k) s += red[k][0][r][tid];
                    int n = np * 16 + (tid & 15);
                    int bb2 = mt * 16 + (tid >> 4) * 4 + r;
                    if (n < 80)
                        out_mel[(size_t)bb2 * 40960 + (size_t)n * 512 + (t - 1)] = s + proj_b[n];
                    else if (n == 80)
                        out_gate[bb2 * 512 + (t - 1)] = s + gate_b[0];
                }
            }
            __syncthreads();
        }
        if (t == 512) break;

        // locproj (block-local)
        {
            int mt = w & 1;
            bf16x8 Af = *(const bf16x8*)&loc_b[mt * 16 + r0][kq];
#pragma unroll
            for (int u = 0; u < 2; ++u) {
                int tc = (w >> 1) * 2 + u;
                bf16x8 Bf = *(const bf16x8*)&ldense_b[(tc * 64 + lane) * 8];
                f32x4 z = {0,0,0,0};
                f32x4 P = __builtin_amdgcn_mfma_f32_16x16x32_bf16(Af, Bf, z, 0, 0, 0);
#pragma unroll
                for (int r = 0; r < 4; ++r)
                    locp[mt * 16 + (lane >> 4) * 4 + r][tc * 16 + r0] = P[r];
            }
        }
        // wait for pq tiles of this batch-half
        {
            int mt = b8 >> 4;
            if (tid < 8) {
                int* p = pq_flag + (mt * 8 + tid) * 16;
                while (__hip_atomic_load(p, __ATOMIC_ACQUIRE, __HIP_MEMORY_SCOPE_AGENT) < t + 1) {}
            }
            __syncthreads();
        }
        // energies for this block's 32-tt slice
        {
            int tt_l = tid >> 4, dg = tid & 15;
            int tt = s8 * 32 + tt_l;
            const float* pqr = pq_g + b8 * 128 + dg * 8;
            const float* pmr = pm + ((size_t)b8 << 15) + (size_t)tt * 128 + dg * 8;
            const float* vr  = vvec + dg * 8;
            float s = 0.f;
#pragma unroll
            for (int h = 0; h < 2; ++h) {
                float4 lp  = *(const float4*)&locp[tt_l][dg * 8 + h * 4];
                float4 pq4 = *(const float4*)(pqr + h * 4);
                float4 pm4 = *(const float4*)(pmr + h * 4);
                float4 v4  = *(const float4*)(vr + h * 4);
                s += ftanh(lp.x + pq4.x + pm4.x) * v4.x;
                s += ftanh(lp.y + pq4.y + pm4.y) * v4.y;
                s += ftanh(lp.z + pq4.z + pm4.z) * v4.z;
                s += ftanh(lp.w + pq4.w + pm4.w) * v4.w;
            }
#pragma unroll
            for (int m = 1; m < 16; m <<= 1) s += __shfl_xor(s, m);
            if (dg == 0) e_g[b8 * 256 + tt] = s;
        }
        __syncthreads();
        if (tid == 0)
            __hip_atomic_store(e_flag + (b8 * 8 + s8) * 16, t + 1,
                               __ATOMIC_RELEASE, __HIP_MEMORY_SCOPE_AGENT);
        if (tid < 8) {
            int* p = e_flag + (b8 * 8 + tid) * 16;
            while (__hip_atomic_load(p, __ATOMIC_ACQUIRE, __HIP_MEMORY_SCOPE_AGENT) < t + 1) {}
        }
        __syncthreads();

        // softmax + ctx slice + state writes
        {
            float e = -3.0e38f, exv = 0.f;
            if (tid < 256) e = (tid < len) ? e_g[b8 * 256 + tid] : -1e9f;
            float m1 = e;
#pragma unroll
            for (int m = 1; m < 64; m <<= 1) m1 = fmaxf(m1, __shfl_xor(m1, m));
            if (tid < 256 && lane == 0) sm_r[w] = m1;
            __syncthreads();
            float mx = fmaxf(fmaxf(sm_r[0], sm_r[1]), fmaxf(sm_r[2], sm_r[3]));
            if (tid < 256) {
                exv = exp2f((e - mx) * 1.4426950408889634f);
                wgt_sh[tid] = exv;
            }
            float s1 = exv;
#pragma unroll
            for (int m = 1; m < 64; m <<= 1) s1 += __shfl_xor(s1, m);
            if (lane == 0) sm_r[8 + w] = s1;
            __syncthreads();
            float tot = sm_r[8] + sm_r[9] + sm_r[10] + sm_r[11];
            float winv = 1.f / tot;
            if (s8 == 0 && tid < 256) {
                float wg = wgt_sh[tid] * winv;
                out_align[(size_t)b8 * 131072 + (size_t)t * 256 + tid] = wg;
                wgt_g[b8 * 256 + tid] = wg;
                awc_g[b8 * 256 + tid] += wg;
            }
            int eo = tid & 63, p = tid >> 6;
            const float* mr = memory + (size_t)b8 * 131072 + s8 * 64 + eo;
            float cs = 0.f;
#pragma unroll 4
            for (int i = 0; i < 32; ++i) {
                int tt = p * 32 + i;
                cs = fmaf(wgt_sh[tt], mr[(size_t)tt * 512], cs);
            }
            redf[p * 64 + eo] = cs;
            __syncthreads();
            if (tid < 64) {
                float s = 0.f;
#pragma unroll
                for (int pp = 0; pp < 8; ++pp) s += redf[pp * 64 + tid];
                ctx_cur[b8 * 512 + s8 * 64 + tid] = __float2bfloat16(s * winv);
            }
        }
        grid_barrier(gslots, 2 * t + 2);
    }
}

// ============================================================
extern "C" void kernel_launch(void* const* d_in, const int* in_sizes, int n_in,
                              void* d_out, int out_size, void* d_ws, size_t ws_size,
                              hipStream_t stream)
{
    const float* memory   = (const float*)d_in[0];
    const float* dec_in   = (const float*)d_in[1];
    const int*   mlen     = (const int*)  d_in[2];
    const float* pw1      = (const float*)d_in[3];
    const float* pw2      = (const float*)d_in[4];
    const float* a_wih    = (const float*)d_in[5];
    const float* a_whh    = (const float*)d_in[6];
    const float* a_b      = (const float*)d_in[7];
    const float* wq       = (const float*)d_in[8];
    const float* wm       = (const float*)d_in[9];
    const float* v        = (const float*)d_in[10];
    const float* lconv    = (const float*)d_in[11];
    const float* ldense   = (const float*)d_in[12];
    const float* d_wih    = (const float*)d_in[13];
    const float* d_whh    = (const float*)d_in[14];
    const float* d_b      = (const float*)d_in[15];
    const float* proj_w   = (const float*)d_in[16];
    const float* proj_b   = (const float*)d_in[17];
    const float* gate_w   = (const float*)d_in[18];
    const float* gate_b   = (const float*)d_in[19];

    char* ws = (char*)d_ws;
    __hip_bfloat16* x2b  = (__hip_bfloat16*)(ws + B_X2);
    float*          pm   = (float*)(ws + B_PM);
    __hip_bfloat16* wswA = (__hip_bfloat16*)(ws + B_WSA);
    __hip_bfloat16* wswD = (__hip_bfloat16*)(ws + B_WSD);
    __hip_bfloat16* wqs  = (__hip_bfloat16*)(ws + B_WQS);
    __hip_bfloat16* wps  = (__hip_bfloat16*)(ws + B_WPS);
    float* outbase = (float*)d_out;

    hipMemsetAsync(ws + B_ZERO_START, 0, B_ZERO_BYTES, stream);
    hipMemsetAsync(ws + B_GBAR, 0, B_BAR_ZERO_BYTES, stream);

    prenet_kernel<<<1024, 256, 0, stream>>>(dec_in, pw1, pw2, x2b);
    pm_kernel<<<dim3(16, 32), 128, 0, stream>>>(memory, wm, pm);
    swizzle_kernel<<<3584, 256, 0, stream>>>(a_wih, 768,  a_whh, 1024, wswA, 1792);
    swizzle_kernel<<<5120, 256, 0, stream>>>(d_wih, 1536, d_whh, 1024, wswD, 2560);
    swizzle_wq<<<64, 256, 0, stream>>>(wq, wqs);
    swizzle_proj<<<72, 256, 0, stream>>>(proj_w, gate_w, wps);

    void* kargs[] = {
        (void*)&memory, (void*)&mlen, (void*)&a_b, (void*)&d_b,
        (void*)&proj_b, (void*)&gate_b, (void*)&lconv, (void*)&ldense,
        (void*)&v, (void*)&ws, (void*)&outbase
    };
    hipLaunchCooperativeKernel((void*)decoder_persistent, dim3(256), dim3(512),
                               kargs, 0, stream);
}